// Round 3
// baseline (55.546 us; speedup 1.0000x reference)
//
#include <hip/hip_runtime.h>
#include <math.h>

#define B_ 8
#define N_ 128
#define M_ 256
#define F_ 256

#define LOG2E2 2.8853900817779268f  // 2*log2(e)

// ---------------------------------------------------------------------------
// K1: u[r][g] = (x[r,:] . Uw[g,:] + Ub[g]) * 2log2e       r = b*N+n (1024 rows)
// ---------------------------------------------------------------------------
#define K1_BM 32
#define K1_BN 64
#define K1_BK 32

__global__ __launch_bounds__(256) void k1_gemm(const float* __restrict__ x,
                                               const float* __restrict__ Uw,
                                               const float* __restrict__ Ub,
                                               float* __restrict__ u) {
  __shared__ float As[K1_BK][K1_BM + 1];
  __shared__ float Bs[K1_BK][K1_BN + 1];
  const int tid  = threadIdx.x;
  const int row0 = blockIdx.x * K1_BM;
  const int col0 = blockIdx.y * K1_BN;
  const int tc = (tid & 15) * 4;
  const int tr = (tid >> 4) * 2;
  float acc[2][4] = {};

  for (int k0 = 0; k0 < F_; k0 += K1_BK) {
    {
      const int r = tid >> 3, c = (tid & 7) * 4;
      const float4 v = *(const float4*)&x[(row0 + r) * F_ + k0 + c];
      As[c + 0][r] = v.x; As[c + 1][r] = v.y; As[c + 2][r] = v.z; As[c + 3][r] = v.w;
    }
#pragma unroll
    for (int i0 = 0; i0 < 2; ++i0) {
      const int i = tid + i0 * 256;
      const int g = i >> 3, c = (i & 7) * 4;
      const float4 v = *(const float4*)&Uw[(col0 + g) * F_ + k0 + c];
      Bs[c + 0][g] = v.x; Bs[c + 1][g] = v.y; Bs[c + 2][g] = v.z; Bs[c + 3][g] = v.w;
    }
    __syncthreads();
#pragma unroll
    for (int k = 0; k < K1_BK; ++k) {
      const float a0 = As[k][tr], a1 = As[k][tr + 1];
      const float b0 = Bs[k][tc + 0], b1 = Bs[k][tc + 1];
      const float b2 = Bs[k][tc + 2], b3 = Bs[k][tc + 3];
      acc[0][0] = fmaf(a0, b0, acc[0][0]);
      acc[0][1] = fmaf(a0, b1, acc[0][1]);
      acc[0][2] = fmaf(a0, b2, acc[0][2]);
      acc[0][3] = fmaf(a0, b3, acc[0][3]);
      acc[1][0] = fmaf(a1, b0, acc[1][0]);
      acc[1][1] = fmaf(a1, b1, acc[1][1]);
      acc[1][2] = fmaf(a1, b2, acc[1][2]);
      acc[1][3] = fmaf(a1, b3, acc[1][3]);
    }
    __syncthreads();
  }
#pragma unroll
  for (int r = 0; r < 2; ++r) {
    float4 o;
    o.x = (acc[r][0] + Ub[col0 + tc + 0]) * LOG2E2;
    o.y = (acc[r][1] + Ub[col0 + tc + 1]) * LOG2E2;
    o.z = (acc[r][2] + Ub[col0 + tc + 2]) * LOG2E2;
    o.w = (acc[r][3] + Ub[col0 + tc + 3]) * LOG2E2;
    *(float4*)&u[(row0 + tr + r) * F_ + col0 + tc] = o;
  }
}

// ---------------------------------------------------------------------------
// K2 v3: block = (nc, b), 512 threads. Tile: 4 n  x  ALL 256 m.
//   thread: m = tid&255, ng = tid>>8 -> handles n = n0+2*ng, n0+2*ng+1.
// Everything LDS-resident: u rows + Ww staged once; y staged in 64-f chunks
// (+4 pad for conflict-free ds_read_b128). Hot loop has NO global loads.
// alpha[n,m] = Wsum - 2*sum_f Ww[f]*rcp(exp2(us[n][f]*y[m][f])+1)
// Row-max over m is FINAL here (block sees all m) -> rowmax[B][N].
// Col-max is partial over the block's 4 n -> cpart[B][32][M].
// ---------------------------------------------------------------------------
#define YF 64              // f-chunk
#define YPAD 4             // pad floats per row (keeps 16B alignment)

__global__ __launch_bounds__(512) void k2_alpha(const float* __restrict__ u,
                                                const float* __restrict__ y,
                                                const float* __restrict__ Ww,
                                                float* __restrict__ rowmax,
                                                float* __restrict__ cpart) {
  __shared__ float ys[M_][YF + YPAD];   // 256 x 68 floats = 68 KB
  __shared__ float us[4][F_];           // 4 KB
  __shared__ float wl[F_];              // 1 KB
  __shared__ float cm[2][M_];           // 2 KB
  __shared__ float rm[8][2];

  const int tid = threadIdx.x;
  const int nc  = blockIdx.x;   // 0..31
  const int b   = blockIdx.y;   // 0..7
  const int n0  = nc * 4;
  const int m   = tid & 255;
  const int w   = tid >> 6;                                  // wave 0..7
  const int ng  = __builtin_amdgcn_readfirstlane(w >> 2);    // 0..1, wave-uniform

  // one-time staging of u rows and Ww
  if (tid < 256) {
    const int r = tid >> 6, c = (tid & 63) * 4;
    const float4 v = *(const float4*)&u[(size_t)(b * N_ + n0 + r) * F_ + c];
    *(float4*)&us[r][c] = v;
  } else if (tid < 320) {
    const int c = (tid - 256) * 4;
    *(float4*)&wl[c] = *(const float4*)&Ww[c];
  }

  float acc0 = 0.f, acc1 = 0.f, wsum = 0.f;

  for (int f0 = 0; f0 < F_; f0 += YF) {
    __syncthreads();   // also covers the one-time staging before first chunk
    // stage y chunk: 256 m x 64 f  (4096 float4 over 512 threads)
#pragma unroll
    for (int k = 0; k < 8; ++k) {
      const int i = tid + k * 512;
      const int ms = i >> 4, c = (i & 15) * 4;
      const float4 v = *(const float4*)&y[(size_t)(b * M_ + ms) * F_ + f0 + c];
      *(float4*)&ys[ms][c] = v;
    }
    __syncthreads();

    for (int fg = 0; fg < YF; fg += 4) {
      const float4 yv  = *(const float4*)&ys[m][fg];              // lane-varying
      const float4 ua  = *(const float4*)&us[ng * 2 + 0][f0 + fg]; // broadcast
      const float4 ub  = *(const float4*)&us[ng * 2 + 1][f0 + fg]; // broadcast
      const float4 wv  = *(const float4*)&wl[f0 + fg];             // broadcast
      const float* yp = (const float*)&yv;
      const float* ap = (const float*)&ua;
      const float* bp = (const float*)&ub;
      const float* wp = (const float*)&wv;
      wsum += wp[0] + wp[1] + wp[2] + wp[3];
#pragma unroll
      for (int j = 0; j < 4; ++j) {
        const float yj = yp[j];
        const float e0 = __builtin_amdgcn_exp2f(ap[j] * yj);
        const float e1 = __builtin_amdgcn_exp2f(bp[j] * yj);
        acc0 = fmaf(wp[j], __builtin_amdgcn_rcpf(e0 + 1.f), acc0);
        acc1 = fmaf(wp[j], __builtin_amdgcn_rcpf(e1 + 1.f), acc1);
      }
    }
  }

  const float alpha0 = wsum - 2.f * acc0;   // (n0+2ng,   m)
  const float alpha1 = wsum - 2.f * acc1;   // (n0+2ng+1, m)

  // ---- final row max over all 256 m ----
  float r0 = alpha0, r1 = alpha1;
#pragma unroll
  for (int s = 32; s; s >>= 1) {
    r0 = fmaxf(r0, __shfl_xor(r0, s));
    r1 = fmaxf(r1, __shfl_xor(r1, s));
  }
  if ((tid & 63) == 0) { rm[w][0] = r0; rm[w][1] = r1; }

  // ---- partial col max over the block's 4 n ----
  cm[ng][m] = fmaxf(alpha0, alpha1);
  __syncthreads();
  if (tid < 4) {
    const int g = tid >> 1, j = tid & 1;
    float v = rm[g * 4][j];
#pragma unroll
    for (int k = 1; k < 4; ++k) v = fmaxf(v, rm[g * 4 + k][j]);
    rowmax[b * N_ + n0 + 2 * g + j] = v;
  }
  if (tid < 256) {
    cpart[((size_t)b * 32 + nc) * M_ + tid] = fmaxf(cm[0][tid], cm[1][tid]);
  }
}

// ---------------------------------------------------------------------------
// K3: per-batch finish. 1024 threads.
// ---------------------------------------------------------------------------
__global__ __launch_bounds__(1024) void k3_final(const float* __restrict__ x,
                                                 const float* __restrict__ y,
                                                 const float* __restrict__ rowmax,
                                                 const float* __restrict__ cpart,
                                                 float* __restrict__ out) {
  const int b = blockIdx.x;
  const int tid = threadIdx.x;
  const int wv = tid >> 6;
  __shared__ float xw[N_];
  __shared__ float yw[M_];
  __shared__ float red[16];
  __shared__ float part[4][256];

  // ---- x attention: softmax over n of rowmax ----
  const float rv = (tid < N_) ? rowmax[b * N_ + tid] : -INFINITY;
  float m1 = rv;
#pragma unroll
  for (int s = 32; s; s >>= 1) m1 = fmaxf(m1, __shfl_xor(m1, s));
  if ((tid & 63) == 0) red[wv] = m1;
  __syncthreads();
  m1 = red[0];
#pragma unroll
  for (int w = 1; w < 16; ++w) m1 = fmaxf(m1, red[w]);
  __syncthreads();
  const float e1 = (tid < N_) ? __expf(rv - m1) : 0.f;
  float s1 = e1;
#pragma unroll
  for (int s = 32; s; s >>= 1) s1 += __shfl_xor(s1, s);
  if ((tid & 63) == 0) red[wv] = s1;
  __syncthreads();
  s1 = 0.f;
#pragma unroll
  for (int w = 0; w < 16; ++w) s1 += red[w];
  if (tid < N_) xw[tid] = e1 / s1;
  __syncthreads();

  // ---- y attention: softmax over m of colmax (reduce 32 partials) ----
  float cv = -INFINITY;
  if (tid < M_) {
#pragma unroll 8
    for (int nc = 0; nc < 32; ++nc)
      cv = fmaxf(cv, cpart[((size_t)b * 32 + nc) * M_ + tid]);
  }
  float m2 = cv;
#pragma unroll
  for (int s = 32; s; s >>= 1) m2 = fmaxf(m2, __shfl_xor(m2, s));
  if ((tid & 63) == 0) red[wv] = m2;
  __syncthreads();
  m2 = red[0];
#pragma unroll
  for (int w = 1; w < 16; ++w) m2 = fmaxf(m2, red[w]);
  __syncthreads();
  const float e2 = (tid < M_) ? __expf(cv - m2) : 0.f;
  float s2 = e2;
#pragma unroll
  for (int s = 32; s; s >>= 1) s2 += __shfl_xor(s2, s);
  if ((tid & 63) == 0) red[wv] = s2;
  __syncthreads();
  s2 = 0.f;
#pragma unroll
  for (int w = 0; w < 16; ++w) s2 += red[w];
  if (tid < M_) yw[tid] = e2 / s2;
  __syncthreads();

  // ---- pooled outputs, 4-way split over sum dimension ----
  const int q = tid >> 8;      // 0..3
  const int f = tid & 255;

  float accx = 0.f;
#pragma unroll 4
  for (int n = q; n < N_; n += 4)
    accx = fmaf(xw[n], x[(size_t)(b * N_ + n) * F_ + f], accx);
  part[q][f] = accx;
  __syncthreads();
  if (tid < 256)
    out[b * (2 * F_) + f] = part[0][f] + part[1][f] + part[2][f] + part[3][f];
  __syncthreads();

  float accy = 0.f;
#pragma unroll 4
  for (int m = q; m < M_; m += 4)
    accy = fmaf(yw[m], y[(size_t)(b * M_ + m) * F_ + f], accy);
  part[q][f] = accy;
  __syncthreads();
  if (tid < 256)
    out[b * (2 * F_) + F_ + f] = part[0][f] + part[1][f] + part[2][f] + part[3][f];
}

// ---------------------------------------------------------------------------
extern "C" void kernel_launch(void* const* d_in, const int* in_sizes, int n_in,
                              void* d_out, int out_size, void* d_ws, size_t ws_size,
                              hipStream_t stream) {
  (void)in_sizes; (void)n_in; (void)out_size; (void)ws_size;
  const float* x  = (const float*)d_in[0];
  const float* y  = (const float*)d_in[1];
  const float* Uw = (const float*)d_in[2];
  const float* Ub = (const float*)d_in[3];
  const float* Ww = (const float*)d_in[4];
  // d_in[5] (W_b) unused: softmax/max pipeline is shift-invariant.

  float* u      = (float*)d_ws;                 // [B][N][F]     262144 f
  float* rowmax = u + B_ * N_ * F_;             // [B][N]          1024 f
  float* cpart  = rowmax + B_ * N_;             // [B][32][M]     65536 f
  float* out    = (float*)d_out;

  k1_gemm<<<dim3((B_ * N_) / K1_BM, F_ / K1_BN), 256, 0, stream>>>(x, Uw, Ub, u);
  k2_alpha<<<dim3(32, B_), 512, 0, stream>>>(u, y, Ww, rowmax, cpart);
  k3_final<<<dim3(B_), 1024, 0, stream>>>(x, y, rowmax, cpart, out);
}